// Round 9
// baseline (214.704 us; speedup 1.0000x reference)
//
#include <hip/hip_runtime.h>
#include <stdint.h>

#define NTOK 16384
#define CDIM 1024
#define DHEAD 256

typedef short s16x8 __attribute__((ext_vector_type(8)));
typedef unsigned short u16x8 __attribute__((ext_vector_type(8)));
typedef _Float16 h16x8 __attribute__((ext_vector_type(8)));
typedef float f32x4 __attribute__((ext_vector_type(4)));
typedef float f32x16 __attribute__((ext_vector_type(16)));

static __device__ __forceinline__ unsigned short f2bf(float f) {
    union { float f; unsigned u; } x; x.f = f;
    unsigned r = (x.u + 0x7fffu + ((x.u >> 16) & 1u)) >> 16;
    return (unsigned short)r;
}
static __device__ __forceinline__ unsigned short f2h(float f) {
    _Float16 h = (_Float16)f;
    return __builtin_bit_cast(unsigned short, h);
}
static __device__ __forceinline__ unsigned cvtpk(float lo, float hi) {
    unsigned r;
    asm("v_cvt_pk_bf16_f32 %0, %1, %2" : "=v"(r) : "v"(lo), "v"(hi));
    return r;
}

// ---------------------------------------------------------------------------
// Kernel 1: partial Gram G[de][e] over an n-chunk + per-channel sums.
// NO LDS, NO BARRIERS: each wave independently computes a 64x64 sub-tile,
// reading q (A) and k (B) fragments directly from global in MFMA lane order
// (lane&31 = channel, (lane>>5)*8+j = n). Each wave-load = 2x128B coalesced
// segments. 2-stage register pipeline; compiler emits exact counted vmcnt.
// Block = (bh,chunk,deq): 4 waves = 4 e-quadrants share q via L1.
// XCD swizzle pins the 4 deq-blocks of a tile to one XCD -> k re-reads hit L2.
// Regs: acc 64 AGPR + ~170 arch < 256 (2 waves/SIMD).
// ---------------------------------------------------------------------------
__global__ __launch_bounds__(256, 2)
void k_gram(const float* __restrict__ q, const float* __restrict__ k,
            unsigned short* __restrict__ Gpart, float* __restrict__ Spart, int nchunk)
{
    const int P   = blockIdx.x;
    const int t8  = P & 7;
    const int m   = P >> 3;
    const int deq = m & 3;
    const int thi = m >> 2;
    const int T   = thi * 8 + t8;            // bh*nchunk + chunk
    const int bh  = T / nchunk;
    const int chunk = T - bh * nchunk;
    const int b = bh >> 2, h = bh & 3;
    const int rows = NTOK / nchunk;
    const int S    = rows >> 4;              // K=16 steps

    const int t = threadIdx.x;
    const int w = t >> 6, lane = t & 63;
    const int l31 = lane & 31, g2 = lane >> 5;
    const int nl  = g2 * 8;

    const size_t rowbase = (size_t)(b * NTOK + chunk * rows + nl) * CDIM + h * DHEAD;
    const float* pq = q + rowbase + deq * 64 + l31;   // A: ch = deq*64 + l31 (+32)
    const float* pk = k + rowbase + w * 64 + l31;     // B: e  = w*64   + l31 (+32)

    float Aa0[8], Aa1[8], Ab0[8], Ab1[8];
    float Ba0[8], Ba1[8], Bb0[8], Bb1[8];

#define LDSTEP(a0, a1, b0, b1, s) do {                                   \
        _Pragma("unroll") for (int j = 0; j < 8; ++j) {                   \
            const size_t o_ = (size_t)((s) * 16 + j) * CDIM;              \
            a0[j] = pq[o_]; a1[j] = pq[o_ + 32];                          \
            b0[j] = pk[o_]; b1[j] = pk[o_ + 32];                          \
        } } while (0)

    float sq0 = 0.f, sq1 = 0.f, sk0 = 0.f, sk1 = 0.f;
    f32x16 acc[2][2];
#pragma unroll
    for (int r = 0; r < 2; ++r)
#pragma unroll
        for (int c = 0; c < 2; ++c)
#pragma unroll
            for (int j = 0; j < 16; ++j) acc[r][c][j] = 0.f;

#define CPSTEP(a0, a1, b0, b1) do {                                       \
        if (w == 0) {                                                      \
            _Pragma("unroll") for (int j = 0; j < 8; ++j) { sq0 += a0[j]; sq1 += a1[j]; } \
        }                                                                  \
        if (deq == 0) {                                                    \
            _Pragma("unroll") for (int j = 0; j < 8; ++j) { sk0 += b0[j]; sk1 += b1[j]; } \
        }                                                                  \
        int4 A0, A1, B0, B1;                                               \
        A0.x = cvtpk(a0[0], a0[1]); A0.y = cvtpk(a0[2], a0[3]);            \
        A0.z = cvtpk(a0[4], a0[5]); A0.w = cvtpk(a0[6], a0[7]);            \
        A1.x = cvtpk(a1[0], a1[1]); A1.y = cvtpk(a1[2], a1[3]);            \
        A1.z = cvtpk(a1[4], a1[5]); A1.w = cvtpk(a1[6], a1[7]);            \
        B0.x = cvtpk(b0[0], b0[1]); B0.y = cvtpk(b0[2], b0[3]);            \
        B0.z = cvtpk(b0[4], b0[5]); B0.w = cvtpk(b0[6], b0[7]);            \
        B1.x = cvtpk(b1[0], b1[1]); B1.y = cvtpk(b1[2], b1[3]);            \
        B1.z = cvtpk(b1[4], b1[5]); B1.w = cvtpk(b1[6], b1[7]);            \
        const s16x8 fA0 = __builtin_bit_cast(s16x8, A0);                   \
        const s16x8 fA1 = __builtin_bit_cast(s16x8, A1);                   \
        const s16x8 fB0 = __builtin_bit_cast(s16x8, B0);                   \
        const s16x8 fB1 = __builtin_bit_cast(s16x8, B1);                   \
        acc[0][0] = __builtin_amdgcn_mfma_f32_32x32x16_bf16(fA0, fB0, acc[0][0], 0, 0, 0); \
        acc[0][1] = __builtin_amdgcn_mfma_f32_32x32x16_bf16(fA0, fB1, acc[0][1], 0, 0, 0); \
        acc[1][0] = __builtin_amdgcn_mfma_f32_32x32x16_bf16(fA1, fB0, acc[1][0], 0, 0, 0); \
        acc[1][1] = __builtin_amdgcn_mfma_f32_32x32x16_bf16(fA1, fB1, acc[1][1], 0, 0, 0); \
    } while (0)

    LDSTEP(Aa0, Aa1, Ab0, Ab1, 0);
    for (int s = 0; s < S; s += 2) {
        if (s + 1 < S) LDSTEP(Ba0, Ba1, Bb0, Bb1, s + 1);
        CPSTEP(Aa0, Aa1, Ab0, Ab1);
        if (s + 2 < S) LDSTEP(Aa0, Aa1, Ab0, Ab1, s + 2);
        if (s + 1 < S) CPSTEP(Ba0, Ba1, Bb0, Bb1);
    }
#undef LDSTEP
#undef CPSTEP

    // ---- channel sums: combine g2 halves; lanes 0..31 store ----
    sq0 += __shfl_xor(sq0, 32); sq1 += __shfl_xor(sq1, 32);
    sk0 += __shfl_xor(sk0, 32); sk1 += __shfl_xor(sk1, 32);
    float* sp = Spart + (size_t)(bh * nchunk + chunk) * 512;
    if (w == 0 && g2 == 0) {
        sp[deq * 64 + l31]      = sq0;
        sp[deq * 64 + 32 + l31] = sq1;
    }
    if (deq == 0 && g2 == 0) {
        sp[256 + w * 64 + l31]      = sk0;
        sp[256 + w * 64 + 32 + l31] = sk1;
    }

    // ---- Gpart fp16 write (C layout: col=l31=e, row=(reg&3)+8*(reg>>2)+4*g2) ----
    unsigned short* gp = Gpart + (size_t)(bh * nchunk + chunk) * 65536;
#pragma unroll
    for (int r = 0; r < 2; ++r)
#pragma unroll
        for (int c = 0; c < 2; ++c)
#pragma unroll
            for (int reg = 0; reg < 16; ++reg) {
                const int de = deq * 64 + r * 32 + (reg & 3) + 8 * (reg >> 2) + 4 * g2;
                const int e  = w * 64 + c * 32 + l31;
                gp[(size_t)de * 256 + e] = f2h(acc[r][c][reg]);
            }
}

// ---------------------------------------------------------------------------
// Kernel 2: fused chunk-reduce + scores + softmax (both branches) + W/beta.
// Wf written row-major [dd][e] bf16.
// ---------------------------------------------------------------------------
__global__ __launch_bounds__(256)
void k_scores(const unsigned short* __restrict__ Gpart, const float* __restrict__ Spart,
              const float* __restrict__ wqg, const float* __restrict__ bqg,
              const float* __restrict__ wkg, const float* __restrict__ bkg,
              const float* __restrict__ wvg, const float* __restrict__ bvg,
              const float* __restrict__ wql, const float* __restrict__ bql,
              const float* __restrict__ wkl, const float* __restrict__ bkl,
              const float* __restrict__ wvl, const float* __restrict__ bvl,
              const float* __restrict__ wp,  const float* __restrict__ bp,
              unsigned short* __restrict__ Wf, float* __restrict__ beta, int nchunk)
{
    __shared__ float sSq[256], sSk[256];
    const int t  = threadIdx.x;
    const int bh = blockIdx.x >> 5;
    const int rg = blockIdx.x & 31;
    const int h  = bh & 3;

    float aq = 0.f, ak = 0.f;
    for (int c = 0; c < nchunk; ++c) {
        const float* sp = Spart + (size_t)(bh * nchunk + c) * 512;
        aq += sp[t]; ak += sp[256 + t];
    }
    sSq[t] = aq; sSk[t] = ak;
    __syncthreads();

    const int dl  = t >> 5;
    const int de  = rg * 8 + dl;
    const int e8  = (t & 31) * 8;
    const int cd  = h * DHEAD + de;
    const int ce0 = h * DHEAD + e8;

    float g[8] = {0.f, 0.f, 0.f, 0.f, 0.f, 0.f, 0.f, 0.f};
    const unsigned short* gpb = Gpart + (size_t)bh * nchunk * 65536 + (size_t)de * 256 + e8;
    for (int c = 0; c < nchunk; ++c) {
        h16x8 v = *reinterpret_cast<const h16x8*>(gpb + (size_t)c * 65536);
#pragma unroll
        for (int j = 0; j < 8; ++j) g[j] += (float)v[j];
    }

    const float sqv = sSq[de];
    float skv[8];
#pragma unroll
    for (int j = 0; j < 8; ++j) skv[j] = sSk[e8 + j];

    float wrow[8] = {0.f, 0.f, 0.f, 0.f, 0.f, 0.f, 0.f, 0.f};
    float bacc = 0.f;
    const float scale = 0.03125f;
#pragma unroll
    for (int br = 0; br < 2; ++br) {
        const float* wq = br ? wql : wqg;  const float* bq = br ? bql : bqg;
        const float* wk = br ? wkl : wkg;  const float* bk = br ? bkl : bkg;
        const float* wv = br ? wvl : wvg;  const float* bv = br ? bvl : bvg;
        const float wqv = wq[cd], bqv = bq[cd];

        float s[8], mm = -1e30f;
#pragma unroll
        for (int j = 0; j < 8; ++j) {
            const float wkv = wk[ce0 + j], bkv = bk[ce0 + j];
            s[j] = scale * (wqv * wkv * g[j] + wqv * bkv * sqv
                            + bqv * wkv * skv[j] + bqv * bkv * 16384.0f);
            mm = fmaxf(mm, s[j]);
        }
#pragma unroll
        for (int off = 16; off; off >>= 1) mm = fmaxf(mm, __shfl_xor(mm, off));
        float p[8], sum = 0.f;
#pragma unroll
        for (int j = 0; j < 8; ++j) { p[j] = __expf(s[j] - mm); sum += p[j]; }
#pragma unroll
        for (int off = 16; off; off >>= 1) sum += __shfl_xor(sum, off);
        const float inv = 1.f / sum;
#pragma unroll
        for (int j = 0; j < 8; ++j) {
            const float a = p[j] * inv;
            wrow[j] += a * wv[ce0 + j];
            bacc    += a * bv[ce0 + j];
        }
    }
    const float wp2 = 2.f * wp[cd];
    u16x8 pw;
#pragma unroll
    for (int j = 0; j < 8; ++j) pw[j] = f2bf(wp2 * wrow[j]);
    *reinterpret_cast<u16x8*>(Wf + (size_t)bh * 65536 + (size_t)de * 256 + e8) = pw;
#pragma unroll
    for (int off = 16; off; off >>= 1) bacc += __shfl_xor(bacc, off);
    if ((t & 31) == 0) beta[bh * 256 + de] = wp2 * bacc + bp[cd];
}

// ---------------------------------------------------------------------------
// Kernel 3: Out[n][dd] = sum_e W[dd][e]*v[n][ce] + beta[dd].
// NO LDS, NO BARRIERS: wave tile 32n x 256dd. A-frag = v rows read directly
// (contraction over ch -> per-lane 2x f32x4, perfectly coalesced). B-frag =
// Wf[dd][e] bf16 dwordx4 (L2-hot; all blocks of bh pinned to XCD bh).
// Regs: acc 128 AGPR + ~110 arch < 256 (2 waves/SIMD).
// ---------------------------------------------------------------------------
__global__ __launch_bounds__(256, 2)
void k_out(const float* __restrict__ v, const unsigned short* __restrict__ Wf,
           const float* __restrict__ beta, float* __restrict__ out)
{
    const int P    = blockIdx.x;
    const int bh   = P & 7;                 // XCD = P%8 -> all tiles of bh co-XCD
    const int tile = P >> 3;
    const int b    = bh >> 2, h = bh & 3;

    const int t = threadIdx.x;
    const int w = t >> 6, lane = t & 63;
    const int l31 = lane & 31, g2 = lane >> 5;
    const int n0 = tile * 128 + w * 32;

    const float* pv = v + (size_t)(b * NTOK + n0 + l31) * CDIM + h * DHEAD + g2 * 8;
    const unsigned short* pw = Wf + (size_t)bh * 65536 + (size_t)l31 * 256 + g2 * 8;

    f32x4 Aa[2], Ab[2];
    u16x8 Ba[8], Bb[8];

#define LDSTEP(av, bv2, ks) do {                                              \
        av[0] = *reinterpret_cast<const f32x4*>(pv + (ks) * 16);               \
        av[1] = *reinterpret_cast<const f32x4*>(pv + (ks) * 16 + 4);           \
        _Pragma("unroll") for (int dg = 0; dg < 8; ++dg)                       \
            bv2[dg] = *reinterpret_cast<const u16x8*>(pw + (size_t)dg * 8192 + (ks) * 16); \
    } while (0)

    f32x16 acc[8];
#pragma unroll
    for (int dg = 0; dg < 8; ++dg)
#pragma unroll
        for (int j = 0; j < 16; ++j) acc[dg][j] = 0.f;

#define CPSTEP(av, bv2) do {                                                  \
        int4 A;                                                               \
        A.x = cvtpk(av[0][0], av[0][1]); A.y = cvtpk(av[0][2], av[0][3]);     \
        A.z = cvtpk(av[1][0], av[1][1]); A.w = cvtpk(av[1][2], av[1][3]);     \
        const s16x8 fA = __builtin_bit_cast(s16x8, A);                        \
        _Pragma("unroll") for (int dg = 0; dg < 8; ++dg)                      \
            acc[dg] = __builtin_amdgcn_mfma_f32_32x32x16_bf16(                \
                fA, __builtin_bit_cast(s16x8, bv2[dg]), acc[dg], 0, 0, 0);    \
    } while (0)

    LDSTEP(Aa, Ba, 0);
#pragma unroll
    for (int ks = 0; ks < 16; ks += 2) {
        if (ks + 1 < 16) LDSTEP(Ab, Bb, ks + 1);
        CPSTEP(Aa, Ba);
        if (ks + 2 < 16) LDSTEP(Aa, Ba, ks + 2);
        if (ks + 1 < 16) CPSTEP(Ab, Bb);
    }
#undef LDSTEP
#undef CPSTEP

    // ---- store: C layout col=l31=dd, row=(reg&3)+8*(reg>>2)+4*g2 = n ----
#pragma unroll
    for (int dg = 0; dg < 8; ++dg) {
        const float bb = beta[bh * 256 + dg * 32 + l31];
#pragma unroll
        for (int reg = 0; reg < 16; ++reg) {
            const int row = (reg & 3) + 8 * (reg >> 2) + 4 * g2;
            out[(size_t)(b * NTOK + n0 + row) * CDIM + h * DHEAD + dg * 32 + l31] =
                acc[dg][reg] + bb;
        }
    }
}

// ---------------------------------------------------------------------------
extern "C" void kernel_launch(void* const* d_in, const int* in_sizes, int n_in,
                              void* d_out, int out_size, void* d_ws, size_t ws_size,
                              hipStream_t stream)
{
    const float* q = (const float*)d_in[0];
    const float* k = (const float*)d_in[1];
    const float* v = (const float*)d_in[2];
    const float* wgt[14];
    for (int i = 0; i < 14; ++i) wgt[i] = (const float*)d_in[3 + i];
    float* out = (float*)d_out;

    int nchunk = 32;
    while (nchunk > 1) {
        size_t need = (size_t)8 * nchunk * 65536 * 2   // Gpart fp16
                    + (size_t)8 * nchunk * 512 * 4     // Spart
                    + (size_t)8 * 65536 * 2            // Wf bf16
                    + (size_t)8 * 256 * 4 + 1024;      // beta + slack
        if (need <= ws_size) break;
        nchunk >>= 1;
    }

    char* p = (char*)d_ws;
    unsigned short* Gpart = (unsigned short*)p; p += (size_t)8 * nchunk * 65536 * 2;
    float* Spart = (float*)p;                   p += (size_t)8 * nchunk * 512 * 4;
    unsigned short* Wf = (unsigned short*)p;    p += (size_t)8 * 65536 * 2;
    float* beta  = (float*)p;

    k_gram<<<dim3(8 * nchunk * 4), dim3(256), 0, stream>>>(q, k, Gpart, Spart, nchunk);
    k_scores<<<dim3(8 * 32), dim3(256), 0, stream>>>(
        Gpart, Spart,
        wgt[0], wgt[1], wgt[2], wgt[3], wgt[4], wgt[5],
        wgt[6], wgt[7], wgt[8], wgt[9], wgt[10], wgt[11],
        wgt[12], wgt[13], Wf, beta, nchunk);
    k_out<<<dim3(8 * 128), dim3(256), 0, stream>>>(v, Wf, beta, out);
}